// Round 6
// baseline (252.814 us; speedup 1.0000x reference)
//
#include <hip/hip_runtime.h>
#include <cfloat>
#include <cstddef>
#include <cstdint>

#define HW 9216
#define MROWS 2304
#define STRIPS 8
#define STRIPW 1152   // 9216/8
#define JTILES 9      // 1152/128

typedef _Float16 half8 __attribute__((ext_vector_type(8)));
typedef float f32x16 __attribute__((ext_vector_type(16)));

// bpack: [2 dtype(hi/lo)][8 bb][8 kseg][9216 j] chunks of 8 halves (16 B)
constexpr size_t BP_CHUNKS_PER_DTYPE = 8ull * 8 * HW;       // 589824 chunks
constexpr size_t OFF_BPACK = 0;                             // 2*589824*16 = 18,874,368 B
constexpr size_t OFF_PVAL  = OFF_BPACK + 2 * BP_CHUNKS_PER_DTYPE * 16;
constexpr size_t OFF_PIDX  = OFF_PVAL + 589824;             // 8bb*8strips*2304 f32
constexpr size_t OFF_ORI   = OFF_PIDX + 589824;
constexpr size_t OFF_CFO   = OFF_ORI  + 36864;
constexpr size_t OFF_CFF   = OFF_CFO  + 147456;
constexpr size_t OFF_SO    = OFF_CFF  + 147456;
constexpr size_t OFF_SF    = OFF_SO   + 1024;
constexpr size_t OFF_INVNF = OFF_SF   + 1024;               // 4*9216 f32 (former norms)

// K0: pre-scale B columns by 1/|b| (NaN for masked cols), split fp16 hi/lo,
// write in MFMA fragment order. br=0 blocks also emit former-pixel inv norms.
__global__ __launch_bounds__(256) void pack_kernel(
    const float* __restrict__ x, const float* __restrict__ flip,
    _Float16* __restrict__ bpack, int* __restrict__ cfo, int* __restrict__ cff,
    float* __restrict__ invnf)
{
    int bb = blockIdx.y;                 // b*2+br
    int b = bb >> 1, br = bb & 1;
    int j = blockIdx.x * 256 + threadIdx.x;   // gridDim.x=36 -> exact
    const float* Bm = br ? (flip + (size_t)b * 64 * HW)
                         : (x + (size_t)b * 128 * HW + (size_t)64 * HW);
    float v[64];
    float norm = 0.f;
    #pragma unroll 16
    for (int k = 0; k < 64; ++k) {
        float a = Bm[(size_t)k * HW + j];
        v[k] = a;
        norm += a * a;
    }
    int r = j / 96, cc = j % 96;
    int cb = br ? 28 : 20;
    bool masked = (r >= 24 && r < 72 && cc >= cb && cc < cb + 48);
    float iv = 1.f / sqrtf(norm);
    if (masked) iv = __builtin_nanf("");

    half8* bp = (half8*)bpack;
    #pragma unroll
    for (int kseg = 0; kseg < 8; ++kseg) {
        half8 hv, lv;
        #pragma unroll
        for (int i = 0; i < 8; ++i) {
            float s = v[kseg * 8 + i] * iv;
            _Float16 h = (_Float16)s;
            hv[i] = h;
            lv[i] = (_Float16)(s - (float)h);
        }
        size_t chunk = ((size_t)bb * 8 + kseg) * HW + j;
        bp[chunk] = hv;
        bp[chunk + BP_CHUNKS_PER_DTYPE] = lv;
    }
    if (br == 0) {
        cfo[b * HW + j] = 0;
        const float* xb = x + (size_t)b * 128 * HW;
        float nf = 0.f;
        #pragma unroll 16
        for (int k = 0; k < 64; ++k) {
            float a = xb[(size_t)k * HW + j];
            nf += a * a;
        }
        invnf[b * HW + j] = 1.f / sqrtf(nf);
    } else {
        cff[b * HW + j] = 0;
    }
}

// K1: MFMA masked-argmax GEMM, fp16 split-3, 32x32x16_f16.
// Single-wave blocks, 64 rows/wave, B operands loaded DIRECTLY global->VGPR in
// fragment order (no LDS, no barriers). grid: x=36 rowgroups(64m), y=8 strips, z=8 bb.
__global__ __launch_bounds__(64, 2) void argmax_kernel(
    const float* __restrict__ x, const _Float16* __restrict__ bpack,
    float* __restrict__ pval, int* __restrict__ pidx)
{
    int rg = blockIdx.x, strip = blockIdx.y, bb = blockIdx.z;
    int b = bb >> 1, br = bb & 1;
    const float* A = x + (size_t)b * 128 * HW;     // former
    int cbase = br ? 28 : 20;

    int lane = threadIdx.x;
    int hf = lane >> 5, l31 = lane & 31;

    // A fragments: wave covers rows mwave..mwave+63 (mt=0: +l31, mt=1: +32+l31)
    int mwave = rg * 64;
    half8 ahf[4][2], alf[4][2];
    #pragma unroll
    for (int mt = 0; mt < 2; ++mt) {
        int m = mwave + mt * 32 + l31;
        int pix = (24 + m / 48) * 96 + cbase + (m % 48);
        #pragma unroll
        for (int ks = 0; ks < 4; ++ks) {
            #pragma unroll
            for (int i = 0; i < 8; ++i) {
                int k = ks * 16 + hf * 8 + i;
                float v = A[(size_t)k * HW + pix];
                _Float16 h = (_Float16)v;
                ahf[ks][mt][i] = h;
                alf[ks][mt][i] = (_Float16)(v - (float)h);
            }
        }
    }

    float rv[32]; int rix[32];
    #pragma unroll
    for (int r = 0; r < 32; ++r) { rv[r] = -FLT_MAX; rix[r] = 0x7fffffff; }

    f32x16 ZERO = {};

    // per-ks fragment base pointers (kseg = ks*2 + hf)
    const half8* bp = (const half8*)bpack;
    const half8* bpH[4];
    #pragma unroll
    for (int ks = 0; ks < 4; ++ks)
        bpH[ks] = bp + ((size_t)bb * 8 + ks * 2 + hf) * HW;

    int jstrip = strip * STRIPW;

    for (int jt = 0; jt < JTILES; ++jt) {
        int jbase = jstrip + jt * 128;
        #pragma unroll
        for (int nt = 0; nt < 4; ++nt) {
            int j = jbase + nt * 32 + l31;
            // load all 8 B fragments for this nt first (independent -> overlapped)
            half8 bh[4], bl[4];
            #pragma unroll
            for (int ks = 0; ks < 4; ++ks) {
                bh[ks] = bpH[ks][j];
                bl[ks] = bpH[ks][j + BP_CHUNKS_PER_DTYPE];
            }
            f32x16 acc0, acc1;
            #pragma unroll
            for (int ks = 0; ks < 4; ++ks) {
                if (ks == 0) {
                    acc0 = __builtin_amdgcn_mfma_f32_32x32x16_f16(ahf[0][0], bh[0], ZERO, 0, 0, 0);
                    acc1 = __builtin_amdgcn_mfma_f32_32x32x16_f16(ahf[0][1], bh[0], ZERO, 0, 0, 0);
                } else {
                    acc0 = __builtin_amdgcn_mfma_f32_32x32x16_f16(ahf[ks][0], bh[ks], acc0, 0, 0, 0);
                    acc1 = __builtin_amdgcn_mfma_f32_32x32x16_f16(ahf[ks][1], bh[ks], acc1, 0, 0, 0);
                }
                acc0 = __builtin_amdgcn_mfma_f32_32x32x16_f16(alf[ks][0], bh[ks], acc0, 0, 0, 0);
                acc1 = __builtin_amdgcn_mfma_f32_32x32x16_f16(alf[ks][1], bh[ks], acc1, 0, 0, 0);
                acc0 = __builtin_amdgcn_mfma_f32_32x32x16_f16(ahf[ks][0], bl[ks], acc0, 0, 0, 0);
                acc1 = __builtin_amdgcn_mfma_f32_32x32x16_f16(ahf[ks][1], bl[ks], acc1, 0, 0, 0);
            }
            // epilogue: pre-scaled scores; masked cols are NaN (never selected by >)
            #pragma unroll
            for (int r = 0; r < 16; ++r) {
                float s0 = acc0[r];
                if (s0 > rv[r])      { rv[r] = s0;      rix[r] = j; }
                float s1 = acc1[r];
                if (s1 > rv[16 + r]) { rv[16 + r] = s1; rix[16 + r] = j; }
            }
        }
    }

    // cross-lane argmax reduce within each 32-lane half (cols), write per-row results
    #pragma unroll
    for (int r = 0; r < 32; ++r) {
        float v = rv[r]; int ix = rix[r];
        #pragma unroll
        for (int off = 1; off <= 16; off <<= 1) {
            float ov = __shfl_xor(v, off, 64);
            int   oi = __shfl_xor(ix, off, 64);
            if (ov > v || (ov == v && oi < ix)) { v = ov; ix = oi; }
        }
        if (l31 == 0) {
            int mt = r >> 4, reg = r & 15;
            int mm = mwave + mt * 32 + (reg & 3) + 8 * (reg >> 2) + 4 * hf;
            pval[((size_t)bb * STRIPS + strip) * MROWS + mm] = v;
            pidx[((size_t)bb * STRIPS + strip) * MROWS + mm] = ix;
        }
    }
}

// K2: merge 8 strips per (bb,m), apply precomputed 1/|a|, ori flag, scatter col flags
__global__ __launch_bounds__(256) void merge_kernel(
    const float* __restrict__ pval, const int* __restrict__ pidx,
    const float* __restrict__ invnf, int* __restrict__ ori,
    int* __restrict__ cfo, int* __restrict__ cff)
{
    int gid = blockIdx.x * 256 + threadIdx.x;      // 36 blocks -> 9216 = 4*2304
    int b = gid / MROWS, m = gid % MROWS;
    float bv[2]; int bi[2];
    #pragma unroll
    for (int br = 0; br < 2; ++br) {
        int bb = b * 2 + br;
        float v = -FLT_MAX; int id = 0x7fffffff;
        #pragma unroll
        for (int s = 0; s < STRIPS; ++s) {
            float pv = pval[((size_t)bb * STRIPS + s) * MROWS + m];
            int   pi = pidx[((size_t)bb * STRIPS + s) * MROWS + m];
            if (pv > v || (pv == v && pi < id)) { v = pv; id = pi; }
        }
        bv[br] = v; bi[br] = id;
    }
    int row = 24 + m / 48, col = m % 48;
    bv[0] *= invnf[b * HW + row * 96 + 20 + col];
    bv[1] *= invnf[b * HW + row * 96 + 28 + col];

    bool o = bv[0] >= bv[1];
    ori[gid] = o ? 1 : 0;
    cfo[b * HW + bi[0]] = 1;
    cff[b * HW + bi[1]] = 1;
}

// K3: S[c] = sum over flagged columns j of Bm[c][j]. One block per (bb, c).
__global__ __launch_bounds__(256) void ssum_kernel(
    const float* __restrict__ x, const float* __restrict__ flip,
    const int* __restrict__ cfo, const int* __restrict__ cff,
    float* __restrict__ So, float* __restrict__ Sf)
{
    int blk = blockIdx.x;                  // 8 = b*2+br
    int c   = blockIdx.y;                  // 64 channels
    int b = blk >> 1, br = blk & 1;
    const float* Bm = br ? (flip + (size_t)b * 64 * HW)
                         : (x + (size_t)b * 128 * HW + (size_t)64 * HW);
    const int* cf = (br ? cff : cfo) + (size_t)b * HW;
    float* S = (br ? Sf : So) + b * 64;

    const float* row = Bm + (size_t)c * HW;
    float acc = 0.f;
    for (int j = threadIdx.x; j < HW; j += 256) {
        if (cf[j]) acc += row[j];
    }
    for (int off = 32; off > 0; off >>= 1) acc += __shfl_down(acc, off, 64);
    __shared__ float part[4];
    int lane = threadIdx.x & 63, w = threadIdx.x >> 6;
    if (lane == 0) part[w] = acc;
    __syncthreads();
    if (threadIdx.x == 0) S[c] = part[0] + part[1] + part[2] + part[3];
}

// K4: assemble output [4][192][9216]
__global__ __launch_bounds__(256) void assemble_kernel(
    const float* __restrict__ x, const int* __restrict__ ori,
    const float* __restrict__ So, const float* __restrict__ Sf,
    float* __restrict__ out)
{
    int idx = blockIdx.x * 256 + threadIdx.x;      // float4 index; grid covers exactly
    const int PER_B4 = 192 * (HW / 4);             // 442368
    int b = idx / PER_B4;
    int rem = idx - b * PER_B4;
    int ch = rem / (HW / 4);
    int p4 = rem % (HW / 4);
    float4 v;
    if (ch < 128) {
        v = reinterpret_cast<const float4*>(x + ((size_t)b * 128 + ch) * HW)[p4];
    } else {
        int c = ch - 128;
        int pix = p4 * 4;
        int r = pix / 96, cc = pix % 96;           // 4 consecutive pixels share the row (96%4==0)
        float so = So[b * 64 + c], sf = Sf[b * 64 + c];
        float vals[4];
        #pragma unroll
        for (int i = 0; i < 4; ++i) {
            int ccc = cc + i;
            if (r >= 24 && r < 72 && ccc >= 20 && ccc < 68) {
                int mm = (r - 24) * 48 + (ccc - 20);
                vals[i] = ori[b * MROWS + mm] ? so : sf;
            } else vals[i] = 0.f;
        }
        v = make_float4(vals[0], vals[1], vals[2], vals[3]);
    }
    reinterpret_cast<float4*>(out)[idx] = v;
}

extern "C" void kernel_launch(void* const* d_in, const int* in_sizes, int n_in,
                              void* d_out, int out_size, void* d_ws, size_t ws_size,
                              hipStream_t stream) {
    const float* x    = (const float*)d_in[0];   // [4,128,9216]
    const float* flip = (const float*)d_in[1];   // [4,64,9216]
    char* w = (char*)d_ws;
    _Float16* bpack = (_Float16*)(w + OFF_BPACK);
    float* pval  = (float*)(w + OFF_PVAL);
    int*   pidx  = (int*)  (w + OFF_PIDX);
    int*   ori   = (int*)  (w + OFF_ORI);
    int*   cfo   = (int*)  (w + OFF_CFO);
    int*   cff   = (int*)  (w + OFF_CFF);
    float* So    = (float*)(w + OFF_SO);
    float* Sf    = (float*)(w + OFF_SF);
    float* invnf = (float*)(w + OFF_INVNF);
    float* out   = (float*)d_out;

    pack_kernel<<<dim3(36, 8), 256, 0, stream>>>(x, flip, bpack, cfo, cff, invnf);
    argmax_kernel<<<dim3(36, 8, 8), 64, 0, stream>>>(x, bpack, pval, pidx);
    merge_kernel<<<36, 256, 0, stream>>>(pval, pidx, invnf, ori, cfo, cff);
    ssum_kernel<<<dim3(8, 64), 256, 0, stream>>>(x, flip, cfo, cff, So, Sf);
    assemble_kernel<<<6912, 256, 0, stream>>>(x, ori, So, Sf, out);
}

// Round 7
// 247.660 us; speedup vs baseline: 1.0208x; 1.0208x over previous
//
#include <hip/hip_runtime.h>
#include <cfloat>
#include <cstddef>
#include <cstdint>

#define HW 9216
#define MROWS 2304
#define STRIPS 18
#define STRIPW 512    // 9216/18
#define JTILES 4      // 512/128

typedef _Float16 half8 __attribute__((ext_vector_type(8)));
typedef float f32x16 __attribute__((ext_vector_type(16)));

// bpack: [2 dtype(hi/lo)][8 bb][8 kseg][9216 j] chunks of 8 halves (16 B)
constexpr size_t BP_CHUNKS_PER_DTYPE = 8ull * 8 * HW;       // 589824 chunks
constexpr size_t OFF_BPACK = 0;                             // 18,874,368 B
constexpr size_t OFF_PVAL  = OFF_BPACK + 2 * BP_CHUNKS_PER_DTYPE * 16;
constexpr size_t OFF_PIDX  = OFF_PVAL + 8ull * STRIPS * MROWS * 4;   // 1,327,104 each
constexpr size_t OFF_ORI   = OFF_PIDX + 8ull * STRIPS * MROWS * 4;
constexpr size_t OFF_CFO   = OFF_ORI  + 36864;
constexpr size_t OFF_CFF   = OFF_CFO  + 147456;
constexpr size_t OFF_SO    = OFF_CFF  + 147456;
constexpr size_t OFF_SF    = OFF_SO   + 1024;
constexpr size_t OFF_INVNF = OFF_SF   + 1024;               // 4*9216 f32 (former norms)

// K0: pre-scale B columns by 1/|b| (NaN for masked cols), split fp16 hi/lo,
// write in MFMA fragment order. 2-pass (norm, then reload+convert) keeps VGPR low.
// br=0 blocks also emit former-pixel inv norms. grid (72, 8), 128 threads.
__global__ __launch_bounds__(128) void pack_kernel(
    const float* __restrict__ x, const float* __restrict__ flip,
    _Float16* __restrict__ bpack, int* __restrict__ cfo, int* __restrict__ cff,
    float* __restrict__ invnf)
{
    int bb = blockIdx.y;                 // b*2+br
    int b = bb >> 1, br = bb & 1;
    int j = blockIdx.x * 128 + threadIdx.x;
    const float* Bm = br ? (flip + (size_t)b * 64 * HW)
                         : (x + (size_t)b * 128 * HW + (size_t)64 * HW);
    // pass 1: norm
    float norm = 0.f;
    #pragma unroll 16
    for (int k = 0; k < 64; ++k) {
        float a = Bm[(size_t)k * HW + j];
        norm += a * a;
    }
    int r = j / 96, cc = j % 96;
    int cb = br ? 28 : 20;
    bool masked = (r >= 24 && r < 72 && cc >= cb && cc < cb + 48);
    float iv = 1.f / sqrtf(norm);
    if (masked) iv = __builtin_nanf("");

    // pass 2: reload (L2-hot), convert, write fragments
    half8* bp = (half8*)bpack;
    #pragma unroll
    for (int kseg = 0; kseg < 8; ++kseg) {
        half8 hv, lv;
        #pragma unroll
        for (int i = 0; i < 8; ++i) {
            float s = Bm[(size_t)(kseg * 8 + i) * HW + j] * iv;
            _Float16 h = (_Float16)s;
            hv[i] = h;
            lv[i] = (_Float16)(s - (float)h);
        }
        size_t chunk = ((size_t)bb * 8 + kseg) * HW + j;
        bp[chunk] = hv;
        bp[chunk + BP_CHUNKS_PER_DTYPE] = lv;
    }
    if (br == 0) {
        cfo[b * HW + j] = 0;
        const float* xb = x + (size_t)b * 128 * HW;
        float nf = 0.f;
        #pragma unroll 16
        for (int k = 0; k < 64; ++k) {
            float a = xb[(size_t)k * HW + j];
            nf += a * a;
        }
        invnf[b * HW + j] = 1.f / sqrtf(nf);
    } else {
        cff[b * HW + j] = 0;
    }
}

// K1: MFMA masked-argmax GEMM, fp16 split-3, 32x32x16_f16.
// 256-thread blocks (4 waves x 64 rows = 256 rows) x 512-j strips.
// grid: x = 144 (bb + 8*strip) [co-XCD for same strip], y = 9 rowgroups.
__global__ __launch_bounds__(256, 2) void argmax_kernel(
    const float* __restrict__ x, const _Float16* __restrict__ bpack,
    float* __restrict__ pval, int* __restrict__ pidx)
{
    int bb = blockIdx.x & 7, strip = blockIdx.x >> 3, rg = blockIdx.y;
    int b = bb >> 1, br = bb & 1;
    const float* A = x + (size_t)b * 128 * HW;     // former
    int cbase = br ? 28 : 20;

    __shared__ _Float16 BB[16384];   // [2 dtype][8 kseg][128 j][8 halves] = 32 KB

    int t = threadIdx.x, lane = t & 63, wv = t >> 6;
    int hf = lane >> 5, l31 = lane & 31;

    // A fragments: wave covers rows mwave..mwave+63 (mt=0: +l31, mt=1: +32+l31)
    int mwave = rg * 256 + wv * 64;
    half8 ahf[4][2], alf[4][2];
    #pragma unroll
    for (int mt = 0; mt < 2; ++mt) {
        int m = mwave + mt * 32 + l31;
        int pix = (24 + m / 48) * 96 + cbase + (m % 48);
        #pragma unroll
        for (int ks = 0; ks < 4; ++ks) {
            #pragma unroll
            for (int i = 0; i < 8; ++i) {
                int k = ks * 16 + hf * 8 + i;
                float v = A[(size_t)k * HW + pix];
                _Float16 h = (_Float16)v;
                ahf[ks][mt][i] = h;
                alf[ks][mt][i] = (_Float16)(v - (float)h);
            }
        }
    }

    float rv[32]; int rix[32];
    #pragma unroll
    for (int r = 0; r < 32; ++r) { rv[r] = -FLT_MAX; rix[r] = 0x7fffffff; }

    f32x16 ZERO = {};

    const half8* bp  = (const half8*)bpack;
    const half8* bb8 = (const half8*)BB;
    int jstrip = strip * STRIPW;

    for (int jt = 0; jt < JTILES; ++jt) {
        int jbase = jstrip + jt * 128;
        __syncthreads();
        // stage 32 KB via global->LDS DMA: 2048 chunks of 16 B, 8 per thread
        #pragma unroll
        for (int iter = 0; iter < 8; ++iter) {
            int slot = t + iter * 256;
            int dtype = slot >> 10, rem = slot & 1023;
            int kseg = rem >> 7, jj = rem & 127;
            size_t gchunk = (size_t)dtype * BP_CHUNKS_PER_DTYPE
                          + ((size_t)bb * 8 + kseg) * HW + jbase + jj;
            __builtin_amdgcn_global_load_lds(
                (const __attribute__((address_space(1))) void*)(bp + gchunk),
                (__attribute__((address_space(3))) void*)((char*)BB + (size_t)slot * 16),
                16, 0, 0);
        }
        __syncthreads();

        #pragma unroll
        for (int nt = 0; nt < 4; ++nt) {
            // load all 8 B fragments for this nt (independent LDS reads)
            half8 bh[4], bl[4];
            #pragma unroll
            for (int ks = 0; ks < 4; ++ks) {
                int kseg = ks * 2 + hf;
                bh[ks] = bb8[kseg * 128 + nt * 32 + l31];
                bl[ks] = bb8[(8 + kseg) * 128 + nt * 32 + l31];
            }
            f32x16 acc0, acc1;
            #pragma unroll
            for (int ks = 0; ks < 4; ++ks) {
                if (ks == 0) {
                    acc0 = __builtin_amdgcn_mfma_f32_32x32x16_f16(ahf[0][0], bh[0], ZERO, 0, 0, 0);
                    acc1 = __builtin_amdgcn_mfma_f32_32x32x16_f16(ahf[0][1], bh[0], ZERO, 0, 0, 0);
                } else {
                    acc0 = __builtin_amdgcn_mfma_f32_32x32x16_f16(ahf[ks][0], bh[ks], acc0, 0, 0, 0);
                    acc1 = __builtin_amdgcn_mfma_f32_32x32x16_f16(ahf[ks][1], bh[ks], acc1, 0, 0, 0);
                }
                acc0 = __builtin_amdgcn_mfma_f32_32x32x16_f16(alf[ks][0], bh[ks], acc0, 0, 0, 0);
                acc1 = __builtin_amdgcn_mfma_f32_32x32x16_f16(alf[ks][1], bh[ks], acc1, 0, 0, 0);
                acc0 = __builtin_amdgcn_mfma_f32_32x32x16_f16(ahf[ks][0], bl[ks], acc0, 0, 0, 0);
                acc1 = __builtin_amdgcn_mfma_f32_32x32x16_f16(ahf[ks][1], bl[ks], acc1, 0, 0, 0);
            }
            // epilogue: pre-scaled scores; masked cols are NaN (never selected by >)
            int j = jbase + nt * 32 + l31;
            #pragma unroll
            for (int r = 0; r < 16; ++r) {
                float s0 = acc0[r];
                if (s0 > rv[r])      { rv[r] = s0;      rix[r] = j; }
                float s1 = acc1[r];
                if (s1 > rv[16 + r]) { rv[16 + r] = s1; rix[16 + r] = j; }
            }
        }
    }

    // cross-lane argmax reduce within each 32-lane half (cols), write per-row results
    #pragma unroll
    for (int r = 0; r < 32; ++r) {
        float v = rv[r]; int ix = rix[r];
        #pragma unroll
        for (int off = 1; off <= 16; off <<= 1) {
            float ov = __shfl_xor(v, off, 64);
            int   oi = __shfl_xor(ix, off, 64);
            if (ov > v || (ov == v && oi < ix)) { v = ov; ix = oi; }
        }
        if (l31 == 0) {
            int mt = r >> 4, reg = r & 15;
            int mm = mwave + mt * 32 + (reg & 3) + 8 * (reg >> 2) + 4 * hf;
            pval[((size_t)bb * STRIPS + strip) * MROWS + mm] = v;
            pidx[((size_t)bb * STRIPS + strip) * MROWS + mm] = ix;
        }
    }
}

// K2: merge 18 strips per (bb,m), apply precomputed 1/|a|, ori flag, scatter col flags
__global__ __launch_bounds__(256) void merge_kernel(
    const float* __restrict__ pval, const int* __restrict__ pidx,
    const float* __restrict__ invnf, int* __restrict__ ori,
    int* __restrict__ cfo, int* __restrict__ cff)
{
    int gid = blockIdx.x * 256 + threadIdx.x;      // 36 blocks -> 9216 = 4*2304
    int b = gid / MROWS, m = gid % MROWS;
    float bv[2]; int bi[2];
    #pragma unroll
    for (int br = 0; br < 2; ++br) {
        int bb = b * 2 + br;
        float v = -FLT_MAX; int id = 0x7fffffff;
        #pragma unroll
        for (int s = 0; s < STRIPS; ++s) {
            float pv = pval[((size_t)bb * STRIPS + s) * MROWS + m];
            int   pi = pidx[((size_t)bb * STRIPS + s) * MROWS + m];
            if (pv > v || (pv == v && pi < id)) { v = pv; id = pi; }
        }
        bv[br] = v; bi[br] = id;
    }
    int row = 24 + m / 48, col = m % 48;
    bv[0] *= invnf[b * HW + row * 96 + 20 + col];
    bv[1] *= invnf[b * HW + row * 96 + 28 + col];

    bool o = bv[0] >= bv[1];
    ori[gid] = o ? 1 : 0;
    cfo[b * HW + bi[0]] = 1;
    cff[b * HW + bi[1]] = 1;
}

// K3: S[c] = sum over flagged columns j of Bm[c][j]. One block per (bb, c).
__global__ __launch_bounds__(256) void ssum_kernel(
    const float* __restrict__ x, const float* __restrict__ flip,
    const int* __restrict__ cfo, const int* __restrict__ cff,
    float* __restrict__ So, float* __restrict__ Sf)
{
    int blk = blockIdx.x;                  // 8 = b*2+br
    int c   = blockIdx.y;                  // 64 channels
    int b = blk >> 1, br = blk & 1;
    const float* Bm = br ? (flip + (size_t)b * 64 * HW)
                         : (x + (size_t)b * 128 * HW + (size_t)64 * HW);
    const int* cf = (br ? cff : cfo) + (size_t)b * HW;
    float* S = (br ? Sf : So) + b * 64;

    const float* row = Bm + (size_t)c * HW;
    float acc = 0.f;
    for (int j = threadIdx.x; j < HW; j += 256) {
        if (cf[j]) acc += row[j];
    }
    for (int off = 32; off > 0; off >>= 1) acc += __shfl_down(acc, off, 64);
    __shared__ float part[4];
    int lane = threadIdx.x & 63, w = threadIdx.x >> 6;
    if (lane == 0) part[w] = acc;
    __syncthreads();
    if (threadIdx.x == 0) S[c] = part[0] + part[1] + part[2] + part[3];
}

// K4: assemble output [4][192][9216]
__global__ __launch_bounds__(256) void assemble_kernel(
    const float* __restrict__ x, const int* __restrict__ ori,
    const float* __restrict__ So, const float* __restrict__ Sf,
    float* __restrict__ out)
{
    int idx = blockIdx.x * 256 + threadIdx.x;      // float4 index; grid covers exactly
    const int PER_B4 = 192 * (HW / 4);             // 442368
    int b = idx / PER_B4;
    int rem = idx - b * PER_B4;
    int ch = rem / (HW / 4);
    int p4 = rem % (HW / 4);
    float4 v;
    if (ch < 128) {
        v = reinterpret_cast<const float4*>(x + ((size_t)b * 128 + ch) * HW)[p4];
    } else {
        int c = ch - 128;
        int pix = p4 * 4;
        int r = pix / 96, cc = pix % 96;           // 4 consecutive pixels share the row (96%4==0)
        float so = So[b * 64 + c], sf = Sf[b * 64 + c];
        float vals[4];
        #pragma unroll
        for (int i = 0; i < 4; ++i) {
            int ccc = cc + i;
            if (r >= 24 && r < 72 && ccc >= 20 && ccc < 68) {
                int mm = (r - 24) * 48 + (ccc - 20);
                vals[i] = ori[b * MROWS + mm] ? so : sf;
            } else vals[i] = 0.f;
        }
        v = make_float4(vals[0], vals[1], vals[2], vals[3]);
    }
    reinterpret_cast<float4*>(out)[idx] = v;
}

extern "C" void kernel_launch(void* const* d_in, const int* in_sizes, int n_in,
                              void* d_out, int out_size, void* d_ws, size_t ws_size,
                              hipStream_t stream) {
    const float* x    = (const float*)d_in[0];   // [4,128,9216]
    const float* flip = (const float*)d_in[1];   // [4,64,9216]
    char* w = (char*)d_ws;
    _Float16* bpack = (_Float16*)(w + OFF_BPACK);
    float* pval  = (float*)(w + OFF_PVAL);
    int*   pidx  = (int*)  (w + OFF_PIDX);
    int*   ori   = (int*)  (w + OFF_ORI);
    int*   cfo   = (int*)  (w + OFF_CFO);
    int*   cff   = (int*)  (w + OFF_CFF);
    float* So    = (float*)(w + OFF_SO);
    float* Sf    = (float*)(w + OFF_SF);
    float* invnf = (float*)(w + OFF_INVNF);
    float* out   = (float*)d_out;

    pack_kernel<<<dim3(72, 8), 128, 0, stream>>>(x, flip, bpack, cfo, cff, invnf);
    argmax_kernel<<<dim3(144, 9), 256, 0, stream>>>(x, bpack, pval, pidx);
    merge_kernel<<<36, 256, 0, stream>>>(pval, pidx, invnf, ori, cfo, cff);
    ssum_kernel<<<dim3(8, 64), 256, 0, stream>>>(x, flip, cfo, cff, So, Sf);
    assemble_kernel<<<6912, 256, 0, stream>>>(x, ori, So, Sf, out);
}

// Round 8
// 203.657 us; speedup vs baseline: 1.2414x; 1.2161x over previous
//
#include <hip/hip_runtime.h>
#include <cfloat>
#include <cstddef>
#include <cstdint>

#define HW 9216
#define MROWS 2304
#define STRIPS 18
#define GPS 32          // 16-col groups per strip (STRIPW 512)
#define NGRP 576        // 9216/16 total groups

typedef _Float16 half8 __attribute__((ext_vector_type(8)));
typedef float f32x4 __attribute__((ext_vector_type(4)));

// bpack (B fragments, 16x16x32 layout): half8 index = (((dt*8+bb)*2 + c)*576 + g)*64 + lane
//   dt: 0=hi 1=lo, c: k-chunk of 32, g: 16-col group, lane = (j&15) + 16*(k-octet within chunk)
// apack (A fragments): half8 index = ((((bb*36+rg)*4 + rt)*2 + c)*2 + dt)*64 + lane
constexpr size_t OFF_BPB  = 0;                         // 18,874,368 B
constexpr size_t OFF_APA  = OFF_BPB + 2ull*8*2*NGRP*64*16;
constexpr size_t OFF_PVAL = OFF_APA + 8ull*36*4*2*2*64*16;     // +4,718,592
constexpr size_t OFF_PIDX = OFF_PVAL + 8ull*STRIPS*MROWS*4;    // 1,327,104 each
constexpr size_t OFF_ORI  = OFF_PIDX + 8ull*STRIPS*MROWS*4;
constexpr size_t OFF_CFO  = OFF_ORI  + 36864;
constexpr size_t OFF_CFF  = OFF_CFO  + 147456;
constexpr size_t OFF_SO   = OFF_CFF  + 147456;
constexpr size_t OFF_SF   = OFF_SO   + 1024;
constexpr size_t OFF_INVA = OFF_SF   + 1024;                   // 8*2304 f32

// K0a: B-side pack. grid (288, 8 bb), 256t. Thread = (col j = blk*32 + t&31, oct = t>>5).
// One pass: 8 loads, LDS norm reduction, scale by 1/|b| (NaN if masked), hi/lo split,
// write one hi + one lo fragment chunk. oct==0 threads also zero cf flags.
__global__ __launch_bounds__(256) void bpack_kernel(
    const float* __restrict__ x, const float* __restrict__ flip,
    half8* __restrict__ bpB, int* __restrict__ cfo, int* __restrict__ cff)
{
    int bb = blockIdx.y, b = bb >> 1, br = bb & 1;
    int t = threadIdx.x, col = t & 31, oct = t >> 5;
    int j = blockIdx.x * 32 + col;
    const float* Bm = br ? (flip + (size_t)b * 64 * HW)
                         : (x + (size_t)b * 128 * HW + (size_t)64 * HW);
    float v[8];
    float part = 0.f;
    #pragma unroll
    for (int e = 0; e < 8; ++e) {
        v[e] = Bm[(size_t)(oct * 8 + e) * HW + j];
        part += v[e] * v[e];
    }
    __shared__ float nsq[8][32];
    __shared__ float ivs[32];
    nsq[oct][col] = part;
    __syncthreads();
    if (oct == 0) {
        float tot = 0.f;
        #pragma unroll
        for (int o = 0; o < 8; ++o) tot += nsq[o][col];
        int r = j / 96, cc = j % 96;
        int cb = br ? 28 : 20;
        bool masked = (r >= 24 && r < 72 && cc >= cb && cc < cb + 48);
        float iv = 1.f / sqrtf(tot);
        ivs[col] = masked ? __builtin_nanf("") : iv;
        if (br == 0) cfo[b * HW + j] = 0; else cff[b * HW + j] = 0;
    }
    __syncthreads();
    float iv = ivs[col];
    half8 hv, lv;
    #pragma unroll
    for (int e = 0; e < 8; ++e) {
        float s = v[e] * iv;
        _Float16 h = (_Float16)s;
        hv[e] = h;
        lv[e] = (_Float16)(s - (float)h);
    }
    int g = j >> 4, n = j & 15, c = oct >> 2, q = oct & 3;
    int lane = n + 16 * q;
    bpB[(((size_t)(0 * 8 + bb) * 2 + c) * NGRP + g) * 64 + lane] = hv;
    bpB[(((size_t)(1 * 8 + bb) * 2 + c) * NGRP + g) * 64 + lane] = lv;
}

// K0b: A-side pack + per-row inverse norms. grid (36 rg, 8 bb), 256t.
// Thread = (row ml = t&63, k-slice s = t>>6 covering k = s*16..s*16+15).
__global__ __launch_bounds__(256) void apack_kernel(
    const float* __restrict__ x, half8* __restrict__ apA, float* __restrict__ invA)
{
    int bb = blockIdx.y, b = bb >> 1, br = bb & 1;
    int rg = blockIdx.x;
    int t = threadIdx.x, ml = t & 63, s = t >> 6;
    int cbase = br ? 28 : 20;
    int m = rg * 64 + ml;
    int pix = (24 + m / 48) * 96 + cbase + (m % 48);
    const float* A = x + (size_t)b * 128 * HW;
    float v[16];
    float part = 0.f;
    #pragma unroll
    for (int e = 0; e < 16; ++e) {
        v[e] = A[(size_t)(s * 16 + e) * HW + pix];
        part += v[e] * v[e];
    }
    __shared__ float red[4][64];
    red[s][ml] = part;
    __syncthreads();
    if (s == 0) {
        float tot = red[0][ml] + red[1][ml] + red[2][ml] + red[3][ml];
        invA[bb * MROWS + m] = 1.f / sqrtf(tot);
    }
    int rt = ml >> 4;
    size_t fragbase = (((size_t)bb * 36 + rg) * 4 + rt) * 2;   // *2 for c, *2 for dt below
    #pragma unroll
    for (int h = 0; h < 2; ++h) {
        int o = 2 * s + h;                 // global k-octet 0..7
        int c = o >> 2, q = o & 3;
        int lane = (ml & 15) + 16 * q;
        half8 hv, lv;
        #pragma unroll
        for (int e = 0; e < 8; ++e) {
            float a = v[h * 8 + e];
            _Float16 hh = (_Float16)a;
            hv[e] = hh;
            lv[e] = (_Float16)(a - (float)hh);
        }
        apA[((fragbase + c) * 2 + 0) * 64 + lane] = hv;
        apA[((fragbase + c) * 2 + 1) * 64 + lane] = lv;
    }
}

// K1: MFMA masked-argmax, fp16 split-3, 16x16x32_f16. Single-wave 64t blocks,
// no LDS, no barriers; A+B read pre-packed; double-buffered B prefetch.
// 64 rows/wave = 4 independent 16-row accumulator chains.
// grid: x = 144 (bb + 8*strip -> XCD locality on bb), y = 36 rowgroups.
__global__ __launch_bounds__(64, 3) void argmax_kernel(
    const half8* __restrict__ apA, const half8* __restrict__ bpB,
    float* __restrict__ pval, int* __restrict__ pidx)
{
    int bb = blockIdx.x & 7, strip = blockIdx.x >> 3, rg = blockIdx.y;
    int lane = threadIdx.x;
    int n = lane & 15;

    // A fragments: ah/al[rt][c]
    half8 ah[4][2], al[4][2];
    {
        size_t base = ((size_t)bb * 36 + rg) * 4;
        #pragma unroll
        for (int rt = 0; rt < 4; ++rt)
            #pragma unroll
            for (int c = 0; c < 2; ++c) {
                ah[rt][c] = apA[(((base + rt) * 2 + c) * 2 + 0) * 64 + lane];
                al[rt][c] = apA[(((base + rt) * 2 + c) * 2 + 1) * 64 + lane];
            }
    }

    float rv[16]; int rix[16];
    #pragma unroll
    for (int r = 0; r < 16; ++r) { rv[r] = -FLT_MAX; rix[r] = 0x7fffffff; }

    const f32x4 ZERO = {};
    int g0 = strip * GPS;

    // B fragment pointers: idx = (((dt*8+bb)*2 + c)*576 + g)*64 + lane
    const half8* pH0 = bpB + (((size_t)(bb) * 2 + 0) * NGRP) * 64 + lane;
    const half8* pH1 = bpB + (((size_t)(bb) * 2 + 1) * NGRP) * 64 + lane;
    const half8* pL0 = bpB + (((size_t)(8 + bb) * 2 + 0) * NGRP) * 64 + lane;
    const half8* pL1 = bpB + (((size_t)(8 + bb) * 2 + 1) * NGRP) * 64 + lane;

    half8 buf0[4], buf1[4];
    auto ldb = [&](half8* d, int g) {
        d[0] = pH0[(size_t)g * 64];
        d[1] = pH1[(size_t)g * 64];
        d[2] = pL0[(size_t)g * 64];
        d[3] = pL1[(size_t)g * 64];
    };
    auto compute = [&](const half8* bf, int gi) {
        f32x4 acc[4];
        #pragma unroll
        for (int rt = 0; rt < 4; ++rt) {
            acc[rt] = __builtin_amdgcn_mfma_f32_16x16x32_f16(ah[rt][0], bf[0], ZERO, 0, 0, 0);
            acc[rt] = __builtin_amdgcn_mfma_f32_16x16x32_f16(al[rt][0], bf[0], acc[rt], 0, 0, 0);
            acc[rt] = __builtin_amdgcn_mfma_f32_16x16x32_f16(ah[rt][0], bf[2], acc[rt], 0, 0, 0);
            acc[rt] = __builtin_amdgcn_mfma_f32_16x16x32_f16(ah[rt][1], bf[1], acc[rt], 0, 0, 0);
            acc[rt] = __builtin_amdgcn_mfma_f32_16x16x32_f16(al[rt][1], bf[1], acc[rt], 0, 0, 0);
            acc[rt] = __builtin_amdgcn_mfma_f32_16x16x32_f16(ah[rt][1], bf[3], acc[rt], 0, 0, 0);
        }
        int j = (g0 + gi) * 16 + n;   // this lane's column
        #pragma unroll
        for (int rt = 0; rt < 4; ++rt)
            #pragma unroll
            for (int r = 0; r < 4; ++r) {
                float s = acc[rt][r];
                int slot = rt * 4 + r;
                if (s > rv[slot]) { rv[slot] = s; rix[slot] = j; }
            }
    };

    ldb(buf0, g0);
    #pragma unroll 1
    for (int gi = 0; gi < GPS; gi += 2) {
        ldb(buf1, g0 + gi + 1);
        compute(buf0, gi);
        int gnext = gi + 2 < GPS ? g0 + gi + 2 : g0 + gi + 1;  // clamp (dummy reload)
        ldb(buf0, gnext);
        compute(buf1, gi + 1);
    }

    // cross-lane argmax over the 16 columns within each 16-lane segment
    #pragma unroll
    for (int slot = 0; slot < 16; ++slot) {
        float v = rv[slot]; int ix = rix[slot];
        #pragma unroll
        for (int off = 1; off <= 8; off <<= 1) {
            float ov = __shfl_xor(v, off, 16);
            int   oi = __shfl_xor(ix, off, 16);
            if (ov > v || (ov == v && oi < ix)) { v = ov; ix = oi; }
        }
        if (n == 0) {
            int q = lane >> 4;               // quad: rows quad*4+reg
            int rt = slot >> 2, r = slot & 3;
            int mm = rg * 64 + rt * 16 + q * 4 + r;
            pval[((size_t)bb * STRIPS + strip) * MROWS + mm] = v;
            pidx[((size_t)bb * STRIPS + strip) * MROWS + mm] = ix;
        }
    }
}

// K2: merge 18 strips per (bb,m), apply precomputed 1/|a|, ori flag, scatter col flags
__global__ __launch_bounds__(256) void merge_kernel(
    const float* __restrict__ pval, const int* __restrict__ pidx,
    const float* __restrict__ invA, int* __restrict__ ori,
    int* __restrict__ cfo, int* __restrict__ cff)
{
    int gid = blockIdx.x * 256 + threadIdx.x;      // 36 blocks -> 9216 = 4*2304
    int b = gid / MROWS, m = gid % MROWS;
    float bv[2]; int bi[2];
    #pragma unroll
    for (int br = 0; br < 2; ++br) {
        int bb = b * 2 + br;
        float v = -FLT_MAX; int id = 0x7fffffff;
        #pragma unroll
        for (int s = 0; s < STRIPS; ++s) {
            float pv = pval[((size_t)bb * STRIPS + s) * MROWS + m];
            int   pi = pidx[((size_t)bb * STRIPS + s) * MROWS + m];
            if (pv > v || (pv == v && pi < id)) { v = pv; id = pi; }
        }
        bv[br] = v * invA[bb * MROWS + m];
        bi[br] = id;
    }
    bool o = bv[0] >= bv[1];
    ori[gid] = o ? 1 : 0;
    cfo[b * HW + bi[0]] = 1;
    cff[b * HW + bi[1]] = 1;
}

// K3: S[c] = sum over flagged columns j of Bm[c][j]. One block per (bb, c).
__global__ __launch_bounds__(256) void ssum_kernel(
    const float* __restrict__ x, const float* __restrict__ flip,
    const int* __restrict__ cfo, const int* __restrict__ cff,
    float* __restrict__ So, float* __restrict__ Sf)
{
    int blk = blockIdx.x;                  // 8 = b*2+br
    int c   = blockIdx.y;                  // 64 channels
    int b = blk >> 1, br = blk & 1;
    const float* Bm = br ? (flip + (size_t)b * 64 * HW)
                         : (x + (size_t)b * 128 * HW + (size_t)64 * HW);
    const int* cf = (br ? cff : cfo) + (size_t)b * HW;
    float* S = (br ? Sf : So) + b * 64;

    const float* row = Bm + (size_t)c * HW;
    float acc = 0.f;
    for (int j = threadIdx.x; j < HW; j += 256) {
        if (cf[j]) acc += row[j];
    }
    for (int off = 32; off > 0; off >>= 1) acc += __shfl_down(acc, off, 64);
    __shared__ float part[4];
    int lane = threadIdx.x & 63, w = threadIdx.x >> 6;
    if (lane == 0) part[w] = acc;
    __syncthreads();
    if (threadIdx.x == 0) S[c] = part[0] + part[1] + part[2] + part[3];
}

// K4: assemble output [4][192][9216]
__global__ __launch_bounds__(256) void assemble_kernel(
    const float* __restrict__ x, const int* __restrict__ ori,
    const float* __restrict__ So, const float* __restrict__ Sf,
    float* __restrict__ out)
{
    int idx = blockIdx.x * 256 + threadIdx.x;      // float4 index; grid covers exactly
    const int PER_B4 = 192 * (HW / 4);             // 442368
    int b = idx / PER_B4;
    int rem = idx - b * PER_B4;
    int ch = rem / (HW / 4);
    int p4 = rem % (HW / 4);
    float4 v;
    if (ch < 128) {
        v = reinterpret_cast<const float4*>(x + ((size_t)b * 128 + ch) * HW)[p4];
    } else {
        int c = ch - 128;
        int pix = p4 * 4;
        int r = pix / 96, cc = pix % 96;           // 4 consecutive pixels share the row (96%4==0)
        float so = So[b * 64 + c], sf = Sf[b * 64 + c];
        float vals[4];
        #pragma unroll
        for (int i = 0; i < 4; ++i) {
            int ccc = cc + i;
            if (r >= 24 && r < 72 && ccc >= 20 && ccc < 68) {
                int mm = (r - 24) * 48 + (ccc - 20);
                vals[i] = ori[b * MROWS + mm] ? so : sf;
            } else vals[i] = 0.f;
        }
        v = make_float4(vals[0], vals[1], vals[2], vals[3]);
    }
    reinterpret_cast<float4*>(out)[idx] = v;
}

extern "C" void kernel_launch(void* const* d_in, const int* in_sizes, int n_in,
                              void* d_out, int out_size, void* d_ws, size_t ws_size,
                              hipStream_t stream) {
    const float* x    = (const float*)d_in[0];   // [4,128,9216]
    const float* flip = (const float*)d_in[1];   // [4,64,9216]
    char* w = (char*)d_ws;
    half8* bpB  = (half8*)(w + OFF_BPB);
    half8* apA  = (half8*)(w + OFF_APA);
    float* pval = (float*)(w + OFF_PVAL);
    int*   pidx = (int*)  (w + OFF_PIDX);
    int*   ori  = (int*)  (w + OFF_ORI);
    int*   cfo  = (int*)  (w + OFF_CFO);
    int*   cff  = (int*)  (w + OFF_CFF);
    float* So   = (float*)(w + OFF_SO);
    float* Sf   = (float*)(w + OFF_SF);
    float* invA = (float*)(w + OFF_INVA);
    float* out  = (float*)d_out;

    bpack_kernel<<<dim3(288, 8), 256, 0, stream>>>(x, flip, bpB, cfo, cff);
    apack_kernel<<<dim3(36, 8), 256, 0, stream>>>(x, apA, invA);
    argmax_kernel<<<dim3(144, 36), 64, 0, stream>>>(apA, bpB, pval, pidx);
    merge_kernel<<<36, 256, 0, stream>>>(pval, pidx, invA, ori, cfo, cff);
    ssum_kernel<<<dim3(8, 64), 256, 0, stream>>>(x, flip, cfo, cff, So, Sf);
    assemble_kernel<<<6912, 256, 0, stream>>>(x, ori, So, Sf, out);
}